// Round 14
// baseline (450.862 us; speedup 1.0000x reference)
//
#include <hip/hip_runtime.h>

#define NV    50000
#define DCH   512
#define NEDGE 150000
#define MPAD  50176   // 392 * 128 = 196 * 256

typedef float  f32x4  __attribute__((ext_vector_type(4)));
typedef __bf16 bf16x8 __attribute__((ext_vector_type(8)));
typedef unsigned short us8 __attribute__((ext_vector_type(8)));

__device__ __forceinline__ unsigned short f2bf(float f) {
  unsigned int u = __builtin_bit_cast(unsigned int, f);
  u += 0x7fffu + ((u >> 16) & 1u);
  return (unsigned short)(u >> 16);
}

__device__ __forceinline__ float bf2f(unsigned short h) {
  return __builtin_bit_cast(float, (unsigned int)h << 16);
}

__device__ __forceinline__ void g2lds16(const void* g, void* l) {
  typedef const __attribute__((address_space(1))) unsigned int* gp_t;
  typedef __attribute__((address_space(3))) unsigned int* lp_t;
  __builtin_amdgcn_global_load_lds((gp_t)g, (lp_t)l, 16, 0, 0);
}

// compiler-only fence: blocks IR + machine-sched motion across a raw s_barrier
__device__ __forceinline__ void barrier_fenced() {
  asm volatile("" ::: "memory");
  __builtin_amdgcn_s_barrier();
  asm volatile("" ::: "memory");
  __builtin_amdgcn_sched_barrier(0);
}

__device__ __forceinline__ void unpack8(us8 v, float4& a, float4& b) {
  a.x = bf2f(v[0]); a.y = bf2f(v[1]); a.z = bf2f(v[2]); a.w = bf2f(v[3]);
  b.x = bf2f(v[4]); b.y = bf2f(v[5]); b.z = bf2f(v[6]); b.w = bf2f(v[7]);
}

// ---------------- structs ----------------
struct WtJob  { const float* w; unsigned short* dst; int ldk, koff; };
struct WtJobs { WtJob j[6]; };
struct CsrP  { const int* ei; int* counts; int* cursor; int* incl; int* off; int* csrc; int* bsum; };
struct Csr3  { CsrP c[3]; };

// ---------------- prep mega-kernel: wt (6 jobs) + cvt_x (2) + hist (3) ----------------
__global__ void prep_k(WtJobs wj, Csr3 cs,
                       const float* __restrict__ xa, const float* __restrict__ xb,
                       unsigned short* __restrict__ oa, unsigned short* __restrict__ ob) {
  int b = blockIdx.x, tid = threadIdx.x;
  if (b < 6144) {
    const WtJob J = wj.j[b >> 10];
    int idx = (b & 1023) * 256 + tid;        // 1024*256 == 512*512 exact
    int k = idx >> 9, n = idx & 511;
    J.dst[(size_t)n * J.ldk + J.koff + k] = f2bf(J.w[(size_t)k * 512 + n]);
  } else if (b < 31144) {
    int rel = b - 6144;
    const float* s = (rel < 12500) ? xa : xb;
    unsigned short* d = (rel < 12500) ? oa : ob;
    int i = (rel % 12500) * 256 + tid;       // 12500*256 == NV*DCH/8 exact
    const float* sp = s + (size_t)i * 8;
    f32x4 u = __builtin_nontemporal_load((const f32x4*)sp);
    f32x4 v = __builtin_nontemporal_load((const f32x4*)(sp + 4));
    us8 o;
    o[0] = f2bf(u[0]); o[1] = f2bf(u[1]); o[2] = f2bf(u[2]); o[3] = f2bf(u[3]);
    o[4] = f2bf(v[0]); o[5] = f2bf(v[1]); o[6] = f2bf(v[2]); o[7] = f2bf(v[3]);
    *(us8*)(d + (size_t)i * 8) = o;
  } else {
    int rel = b - 31144;
    const CsrP C = cs.c[rel / 587];
    int e = (rel % 587) * 256 + tid;
    if (e < NEDGE) atomicAdd(&C.counts[C.ei[NEDGE + e]], 1);
  }
}

// ---------------- CSR scans (z-batched over the 3 edge types) ----------------
__global__ void scan1(Csr3 cs) {
  const CsrP C = cs.c[blockIdx.z];
  __shared__ int sm[1024];
  int t = threadIdx.x, b = blockIdx.x;
  int i = b * 1024 + t;
  int v = (i < NV) ? C.counts[i] : 0;
  sm[t] = v; __syncthreads();
  for (int off = 1; off < 1024; off <<= 1) {
    int x = sm[t];
    int y = (t >= off) ? sm[t - off] : 0;
    __syncthreads();
    sm[t] = x + y;
    __syncthreads();
  }
  if (i < NV) C.incl[i] = sm[t];
  if (t == 1023) C.bsum[b] = sm[t];
}

__global__ void scan3(Csr3 cs) {
  const CsrP C = cs.c[blockIdx.z];
  int i = blockIdx.x * 256 + threadIdx.x;
  if (i < NV) {
    int nb = i >> 10;
    int run = 0;
    for (int j = 0; j < nb; ++j) run += C.bsum[j];
    int v = C.incl[i] - C.counts[i] + run;
    C.off[i] = v;
    C.cursor[i] = v;
  } else if (i == NV) {
    C.off[NV] = NEDGE;
  }
}

__global__ void fill_csr(Csr3 cs) {
  const CsrP C = cs.c[blockIdx.z];
  int e = blockIdx.x * 256 + threadIdx.x;
  if (e >= NEDGE) return;
  int d = C.ei[NEDGE + e];
  int pos = atomicAdd(&C.cursor[d], 1);
  C.csrc[pos] = C.ei[e];
}

// ---------------- gather, split per (node, edge-type): z in {0:aa, 1:ba, 2:ab} ----
struct GatherJob { const unsigned short* xdst; const unsigned short* xsrc;
                   const int* off; const int* csrc; unsigned short* hb; };
struct GatherJobs { GatherJob j[3]; };

__global__ void gather3(GatherJobs gj) {
  const GatherJob G = gj.j[blockIdx.z];
  int g = blockIdx.x * 256 + threadIdx.x;
  int node = g >> 6, lane = g & 63;
  size_t obase = (size_t)node * DCH + lane * 8;
  if (node >= NV) {
    us8 z = {0, 0, 0, 0, 0, 0, 0, 0};
    *(us8*)(G.hb + obase) = z;
    return;
  }
  float4 a, b;
  unpack8(*(const us8*)(G.xdst + obase), a, b);
  int i = G.off[node], s1 = G.off[node + 1];
  for (; i + 1 < s1; i += 2) {
    us8 vA = *(const us8*)(G.xsrc + (size_t)G.csrc[i]     * DCH + lane * 8);
    us8 vB = *(const us8*)(G.xsrc + (size_t)G.csrc[i + 1] * DCH + lane * 8);
    float4 a0, b0, a1, b1;
    unpack8(vA, a0, b0);
    unpack8(vB, a1, b1);
    a.x += a0.x + a1.x; a.y += a0.y + a1.y; a.z += a0.z + a1.z; a.w += a0.w + a1.w;
    b.x += b0.x + b1.x; b.y += b0.y + b1.y; b.z += b0.z + b1.z; b.w += b0.w + b1.w;
  }
  if (i < s1) {
    us8 v = *(const us8*)(G.xsrc + (size_t)G.csrc[i] * DCH + lane * 8);
    float4 a0, b0;
    unpack8(v, a0, b0);
    a.x += a0.x; a.y += a0.y; a.z += a0.z; a.w += a0.w;
    b.x += b0.x; b.y += b0.y; b.z += b0.z; b.w += b0.w;
  }
  us8 o;
  o[0] = f2bf(a.x); o[1] = f2bf(a.y); o[2] = f2bf(a.z); o[3] = f2bf(a.w);
  o[4] = f2bf(b.x); o[5] = f2bf(b.y); o[6] = f2bf(b.z); o[7] = f2bf(b.w);
  *(us8*)(G.hb + obase) = o;
}

// ---------------- GEMM: BK=32, 4-buffer ring, counted vmcnt, FENCED barriers ------
// r13 ring failed from compiler hoisting ds_reads above the raw s_barrier (rule #18
// family: s_barrier is not a compiler memory fence). Fix: barrier_fenced() =
// ""-asm memory clobber + s_barrier + clobber + sched_barrier(0) at every barrier.
// Ring of 4 x 16KB LDS buffers; stage tile t+3 per iter; vmcnt(8) per tile (never 0
// in steady state). Race-free: buffer (t+3)&3 last read at t-1, barrier between.
// LDS granule swizzle slot=(kq+(row>>1))&3 -> 2 lanes/slot (free). Same k-order as r7.
// Grid MUST be (4, 392, z): nwg=1568=8*196 -> exact XCD-chunked swizzle.
struct GemmJob  { const unsigned short* A; int lda; const unsigned short* Bt; int ldb;
                  const float* bias_a; const float* bias_b; void* out; int ldc; int col_off; };
struct GemmJobs { GemmJob j[3]; };

template<int MODE>
__global__ void gemm_tile(GemmJobs jobs) {
  const GemmJob J = jobs.j[blockIdx.z];
  __shared__ __align__(16) char smem[65536];   // 4 ring buffers x (A 8KB + B 8KB)
  const int t = threadIdx.x;
  const int wave = t >> 6, lane = t & 63;
  const int wr = wave >> 1, wc = wave & 1;

  // exact XCD-chunked swizzle (nwg = 1568 = 8 * 196)
  const int flat = blockIdx.x + (blockIdx.y << 2);
  const int wgid = (flat & 7) * 196 + (flat >> 3);
  const int row_base = (wgid >> 2) * 128;
  const int col_base = (wgid & 3) * 128;

  const int rl = lane & 15, kq = lane >> 4;
  const int lda = J.lda, ldb = J.ldb;
  const int ktiles = ldb >> 5;                 // K/32: 16 or 32 (>=4 required)

  // per-thread staging: granule q -> row=q>>2, slot c=q&3; slot holds src granule (c-(r>>1))&3
  const int q0 = t, q1 = 256 + t;
  const int r0 = q0 >> 2, c0 = q0 & 3, cg0 = (c0 - (r0 >> 1)) & 3;
  const int r1 = q1 >> 2, c1 = q1 & 3, cg1 = (c1 - (r1 >> 1)) & 3;
  const unsigned short* gA0 = J.A + (size_t)(row_base + r0) * lda + cg0 * 8;
  const unsigned short* gA1 = J.A + (size_t)(row_base + r1) * lda + cg1 * 8;
  const unsigned short* gB0 = J.Bt + (size_t)(col_base + r0) * ldb + cg0 * 8;
  const unsigned short* gB1 = J.Bt + (size_t)(col_base + r1) * ldb + cg1 * 8;
  const int dA0 = q0 * 16, dA1 = q1 * 16;
  const int dB0 = 8192 + q0 * 16, dB1 = 8192 + q1 * 16;

  // per-lane fragment offsets (slot = (kq + (row>>1)) & 3)
  int aoff[4], boff[4];
#pragma unroll
  for (int m = 0; m < 4; ++m) {
    int row = wr * 64 + m * 16 + rl;
    aoff[m] = (row * 4 + ((kq + (row >> 1)) & 3)) * 16;
  }
#pragma unroll
  for (int n = 0; n < 4; ++n) {
    int col = wc * 64 + n * 16 + rl;
    boff[n] = 8192 + (col * 4 + ((kq + (col >> 1)) & 3)) * 16;
  }

  f32x4 acc[4][4] = {};

  auto stage = [&](int bufbase, int kt) {
    const int ko = kt << 5;                    // 32 elements per K-tile
    g2lds16(gA0 + ko, smem + bufbase + dA0);
    g2lds16(gA1 + ko, smem + bufbase + dA1);
    g2lds16(gB0 + ko, smem + bufbase + dB0);
    g2lds16(gB1 + ko, smem + bufbase + dB1);
  };
  auto compute = [&](int bufbase) {
    bf16x8 af[4], bfr[4];
#pragma unroll
    for (int m = 0; m < 4; ++m) af[m] = *(const bf16x8*)(smem + bufbase + aoff[m]);
#pragma unroll
    for (int n = 0; n < 4; ++n) bfr[n] = *(const bf16x8*)(smem + bufbase + boff[n]);
#pragma unroll
    for (int m = 0; m < 4; ++m)
#pragma unroll
      for (int n = 0; n < 4; ++n)
        acc[m][n] = __builtin_amdgcn_mfma_f32_16x16x32_bf16(af[m], bfr[n], acc[m][n], 0, 0, 0);
  };

  // prologue: stage tiles 0,1,2; wait for tile0 (oldest 4 of 12)
  stage(0, 0);
  stage(16384, 1);
  stage(32768, 2);
  asm volatile("s_waitcnt vmcnt(8)" ::: "memory");
  barrier_fenced();

  // steady state: stage t+3, compute t, vmcnt(8), fenced barrier
  for (int kt = 0; kt < ktiles - 3; ++kt) {
    stage(((kt + 3) & 3) << 14, kt + 3);
    compute((kt & 3) << 14);
    asm volatile("s_waitcnt vmcnt(8)" ::: "memory");
    barrier_fenced();
  }
  // tail: drain 8 -> 4 -> 0
  compute(((ktiles - 3) & 3) << 14);
  asm volatile("s_waitcnt vmcnt(4)" ::: "memory");
  barrier_fenced();
  compute(((ktiles - 2) & 3) << 14);
  asm volatile("s_waitcnt vmcnt(0)" ::: "memory");
  barrier_fenced();
  compute(((ktiles - 1) & 3) << 14);
  __syncthreads();   // full drain before epilogue reuses smem

  // ---- epilogue: LDS repack -> coalesced stores (r7-proven) ----
  float bb[4];
#pragma unroll
  for (int n = 0; n < 4; ++n) {
    int col = col_base + wc * 64 + n * 16 + rl;
    bb[n] = J.bias_a[col] + ((MODE == 1 && J.bias_b) ? J.bias_b[col] : 0.0f);
  }

  if (MODE == 0) {
    unsigned short* Ch = (unsigned short*)smem;   // [128][128] bf16 = 32 KB
#pragma unroll
    for (int m = 0; m < 4; ++m)
#pragma unroll
      for (int n = 0; n < 4; ++n) {
        int col = wc * 64 + n * 16 + rl;
#pragma unroll
        for (int j = 0; j < 4; ++j) {
          int row = wr * 64 + m * 16 + kq * 4 + j;
          float v = fmaxf(acc[m][n][j] + bb[n], 0.0f);
          Ch[row * 128 + col] = f2bf(v);
        }
      }
    __syncthreads();
    unsigned short* out = (unsigned short*)J.out;
#pragma unroll
    for (int i = 0; i < 8; ++i) {
      int f = i * 256 + t;            // us8 granules, 2048 total
      int rloc = f >> 4, c8 = f & 15;
      us8 v = *(const us8*)&Ch[rloc * 128 + c8 * 8];
      *(us8*)&out[(size_t)(row_base + rloc) * J.ldc + J.col_off + col_base + c8 * 8] = v;
    }
  } else {
    float* Cf = (float*)smem;                     // [64][128] f32 per round
    float* out = (float*)J.out;
#pragma unroll
    for (int p = 0; p < 2; ++p) {
      __syncthreads();
      if (wr == p) {
#pragma unroll
        for (int m = 0; m < 4; ++m)
#pragma unroll
          for (int n = 0; n < 4; ++n) {
            int col = wc * 64 + n * 16 + rl;
#pragma unroll
            for (int j = 0; j < 4; ++j) {
              int rloc = m * 16 + kq * 4 + j;
              Cf[rloc * 128 + col] = acc[m][n][j] + bb[n];
            }
          }
      }
      __syncthreads();
#pragma unroll
      for (int i = 0; i < 8; ++i) {
        int f = i * 256 + t;          // float4 granules, 2048 total
        int rloc = f >> 5, c4 = f & 31;
        int grow = row_base + p * 64 + rloc;
        if (grow < NV) {
          f32x4 v = *(const f32x4*)&Cf[rloc * 128 + c4 * 4];
          __builtin_nontemporal_store(v, (f32x4*)&out[(size_t)grow * J.ldc + col_base + c4 * 4]);
        }
      }
    }
  }
}

extern "C" void kernel_launch(void* const* d_in, const int* in_sizes, int n_in,
                              void* d_out, int out_size, void* d_ws, size_t ws_size,
                              hipStream_t stream) {
  const float* x_a  = (const float*)d_in[0];
  const float* x_b  = (const float*)d_in[1];
  const int* ei_aa  = (const int*)d_in[2];
  const int* ei_ab  = (const int*)d_in[3];
  const int* ei_ba  = (const int*)d_in[4];
  const float* w1_aa = (const float*)d_in[5];
  const float* b1_aa = (const float*)d_in[6];
  const float* w2_aa = (const float*)d_in[7];
  const float* b2_aa = (const float*)d_in[8];
  const float* w1_ab = (const float*)d_in[9];
  const float* b1_ab = (const float*)d_in[10];
  const float* w2_ab = (const float*)d_in[11];
  const float* b2_ab = (const float*)d_in[12];
  const float* w1_ba = (const float*)d_in[13];
  const float* b1_ba = (const float*)d_in[14];
  const float* w2_ba = (const float*)d_in[15];
  const float* b2_ba = (const float*)d_in[16];

  char* ws = (char*)d_ws;
  const size_t szH  = (size_t)MPAD * DCH * 2;          // bf16 [MPAD][512]
  const size_t szH2 = (size_t)MPAD * DCH * 2 * 2;      // bf16 [MPAD][1024]
  const size_t szX  = (size_t)NV * DCH * 2;            // bf16 [NV][512]
  size_t o = 0;
  unsigned short* hb_aa = (unsigned short*)(ws + o); o += szH;
  unsigned short* hb_ba = (unsigned short*)(ws + o); o += szH;
  unsigned short* hb_ab = (unsigned short*)(ws + o); o += szH;
  unsigned short* H1c   = (unsigned short*)(ws + o); o += szH2;  // [MPAD][1024]
  unsigned short* H1ab  = (unsigned short*)(ws + o); o += szH;
  unsigned short* xa16  = (unsigned short*)(ws + o); o += szX;
  unsigned short* xb16  = (unsigned short*)(ws + o); o += szX;
  unsigned short* w1t_aa = (unsigned short*)(ws + o); o += 512 * 512 * 2;
  unsigned short* w1t_ba = (unsigned short*)(ws + o); o += 512 * 512 * 2;
  unsigned short* w1t_ab = (unsigned short*)(ws + o); o += 512 * 512 * 2;
  unsigned short* w2tc   = (unsigned short*)(ws + o); o += 512 * 1024 * 2;
  unsigned short* w2t_ab = (unsigned short*)(ws + o); o += 512 * 512 * 2;

  int* counts3 = (int*)(ws + o); o += (size_t)3 * NV * 4;   // one memset

  Csr3 cs;
  const int* eis[3] = { ei_aa, ei_ab, ei_ba };
  for (int tI = 0; tI < 3; ++tI) {
    cs.c[tI].ei     = eis[tI];
    cs.c[tI].counts = counts3 + (size_t)tI * NV;
    cs.c[tI].cursor = (int*)(ws + o); o += (size_t)NV * 4;
    cs.c[tI].incl   = (int*)(ws + o); o += (size_t)NV * 4;
    cs.c[tI].off    = (int*)(ws + o); o += ((size_t)NV + 4) * 4;
    cs.c[tI].csrc   = (int*)(ws + o); o += (size_t)NEDGE * 4;
    cs.c[tI].bsum   = (int*)(ws + o); o += 64 * 4;
  }

  float* out_a = (float*)d_out;
  float* out_b = out_a + (size_t)NV * DCH;

  WtJobs wj;
  wj.j[0] = { w1_aa, w1t_aa, 512, 0 };
  wj.j[1] = { w1_ba, w1t_ba, 512, 0 };
  wj.j[2] = { w1_ab, w1t_ab, 512, 0 };
  wj.j[3] = { w2_aa, w2tc, 1024, 0 };
  wj.j[4] = { w2_ba, w2tc, 1024, 512 };
  wj.j[5] = { w2_ab, w2t_ab, 512, 0 };

  // 1) zero histograms
  (void)hipMemsetAsync(counts3, 0, (size_t)3 * NV * 4, stream);
  // 2) prep: wt + cvt_x + hist in one launch (independent segments)
  prep_k<<<32905, 256, 0, stream>>>(wj, cs, x_a, x_b, xa16, xb16);
  // 3-5) CSR: scan1, scan3', fill
  scan1<<<dim3(49, 1, 3), 1024, 0, stream>>>(cs);
  scan3<<<dim3(196, 1, 3), 256, 0, stream>>>(cs);
  fill_csr<<<dim3(587, 1, 3), 256, 0, stream>>>(cs);
  // 6) gather, one wave per (node, type): z=0 aa (a<-a), z=1 ba (a<-b), z=2 ab (b<-a)
  GatherJobs gj;
  gj.j[0] = { xa16, xa16, cs.c[0].off, cs.c[0].csrc, hb_aa };
  gj.j[1] = { xa16, xb16, cs.c[2].off, cs.c[2].csrc, hb_ba };
  gj.j[2] = { xb16, xa16, cs.c[1].off, cs.c[1].csrc, hb_ab };
  gather3<<<dim3(MPAD / 4, 1, 3), 256, 0, stream>>>(gj);

  // 7) layer 1: 3 GEMMs in one launch (K=512)
  GemmJobs g1;
  g1.j[0] = { hb_aa, 512, w1t_aa, 512, b1_aa, nullptr, H1c,  1024, 0 };
  g1.j[1] = { hb_ba, 512, w1t_ba, 512, b1_ba, nullptr, H1c,  1024, 512 };
  g1.j[2] = { hb_ab, 512, w1t_ab, 512, b1_ab, nullptr, H1ab, 512,  0 };
  gemm_tile<0><<<dim3(4, 392, 3), 256, 0, stream>>>(g1);

  // 8) layer 2: merged-K GEMM (aa+ba, K=1024) and ab GEMM (K=512)
  GemmJobs g2;
  g2.j[0] = { H1c,  1024, w2tc,   1024, b2_aa, b2_ba,  out_a, 512, 0 };
  g2.j[1] = { H1ab, 512,  w2t_ab, 512,  b2_ab, nullptr, out_b, 512, 0 };
  g2.j[2] = g2.j[1];   // unused (grid z=2)
  gemm_tile<1><<<dim3(4, 392, 2), 256, 0, stream>>>(g2);
}

// Round 15
// 428.822 us; speedup vs baseline: 1.0514x; 1.0514x over previous
//
#include <hip/hip_runtime.h>

#define NV    50000
#define DCH   512
#define NEDGE 150000
#define MPAD  50176   // 196 * 256

typedef float  f32x4  __attribute__((ext_vector_type(4)));
typedef __bf16 bf16x8 __attribute__((ext_vector_type(8)));
typedef unsigned short us8 __attribute__((ext_vector_type(8)));

__device__ __forceinline__ unsigned short f2bf(float f) {
  unsigned int u = __builtin_bit_cast(unsigned int, f);
  u += 0x7fffu + ((u >> 16) & 1u);
  return (unsigned short)(u >> 16);
}

__device__ __forceinline__ float bf2f(unsigned short h) {
  return __builtin_bit_cast(float, (unsigned int)h << 16);
}

__device__ __forceinline__ void g2lds16(const void* g, void* l) {
  typedef const __attribute__((address_space(1))) unsigned int* gp_t;
  typedef __attribute__((address_space(3))) unsigned int* lp_t;
  __builtin_amdgcn_global_load_lds((gp_t)g, (lp_t)l, 16, 0, 0);
}

__device__ __forceinline__ void unpack8(us8 v, float4& a, float4& b) {
  a.x = bf2f(v[0]); a.y = bf2f(v[1]); a.z = bf2f(v[2]); a.w = bf2f(v[3]);
  b.x = bf2f(v[4]); b.y = bf2f(v[5]); b.z = bf2f(v[6]); b.w = bf2f(v[7]);
}

// ---------------- structs ----------------
struct WtJob  { const float* w; unsigned short* dst; int ldk, koff; };
struct WtJobs { WtJob j[6]; };
struct CsrP  { const int* ei; int* counts; int* cursor; int* incl; int* off; int* csrc; int* bsum; };
struct Csr3  { CsrP c[3]; };

// ---------------- prep mega-kernel: wt (6 jobs) + cvt_x (2) + hist (3) ----------------
__global__ void prep_k(WtJobs wj, Csr3 cs,
                       const float* __restrict__ xa, const float* __restrict__ xb,
                       unsigned short* __restrict__ oa, unsigned short* __restrict__ ob) {
  int b = blockIdx.x, tid = threadIdx.x;
  if (b < 6144) {
    const WtJob J = wj.j[b >> 10];
    int idx = (b & 1023) * 256 + tid;        // 1024*256 == 512*512 exact
    int k = idx >> 9, n = idx & 511;
    J.dst[(size_t)n * J.ldk + J.koff + k] = f2bf(J.w[(size_t)k * 512 + n]);
  } else if (b < 31144) {
    int rel = b - 6144;
    const float* s = (rel < 12500) ? xa : xb;
    unsigned short* d = (rel < 12500) ? oa : ob;
    int i = (rel % 12500) * 256 + tid;       // 12500*256 == NV*DCH/8 exact
    const float* sp = s + (size_t)i * 8;
    f32x4 u = __builtin_nontemporal_load((const f32x4*)sp);
    f32x4 v = __builtin_nontemporal_load((const f32x4*)(sp + 4));
    us8 o;
    o[0] = f2bf(u[0]); o[1] = f2bf(u[1]); o[2] = f2bf(u[2]); o[3] = f2bf(u[3]);
    o[4] = f2bf(v[0]); o[5] = f2bf(v[1]); o[6] = f2bf(v[2]); o[7] = f2bf(v[3]);
    *(us8*)(d + (size_t)i * 8) = o;
  } else {
    int rel = b - 31144;
    const CsrP C = cs.c[rel / 587];
    int e = (rel % 587) * 256 + tid;
    if (e < NEDGE) atomicAdd(&C.counts[C.ei[NEDGE + e]], 1);
  }
}

// ---------------- CSR scans (z-batched over the 3 edge types) ----------------
__global__ void scan1(Csr3 cs) {
  const CsrP C = cs.c[blockIdx.z];
  __shared__ int sm[1024];
  int t = threadIdx.x, b = blockIdx.x;
  int i = b * 1024 + t;
  int v = (i < NV) ? C.counts[i] : 0;
  sm[t] = v; __syncthreads();
  for (int off = 1; off < 1024; off <<= 1) {
    int x = sm[t];
    int y = (t >= off) ? sm[t - off] : 0;
    __syncthreads();
    sm[t] = x + y;
    __syncthreads();
  }
  if (i < NV) C.incl[i] = sm[t];
  if (t == 1023) C.bsum[b] = sm[t];
}

__global__ void scan3(Csr3 cs) {
  const CsrP C = cs.c[blockIdx.z];
  int i = blockIdx.x * 256 + threadIdx.x;
  if (i < NV) {
    int nb = i >> 10;
    int run = 0;
    for (int j = 0; j < nb; ++j) run += C.bsum[j];
    int v = C.incl[i] - C.counts[i] + run;
    C.off[i] = v;
    C.cursor[i] = v;
  } else if (i == NV) {
    C.off[NV] = NEDGE;
  }
}

__global__ void fill_csr(Csr3 cs) {
  const CsrP C = cs.c[blockIdx.z];
  int e = blockIdx.x * 256 + threadIdx.x;
  if (e >= NEDGE) return;
  int d = C.ei[NEDGE + e];
  int pos = atomicAdd(&C.cursor[d], 1);
  C.csrc[pos] = C.ei[e];
}

// ---------------- gather, split per (node, edge-type): z in {0:aa, 1:ba, 2:ab} ----
struct GatherJob { const unsigned short* xdst; const unsigned short* xsrc;
                   const int* off; const int* csrc; unsigned short* hb; };
struct GatherJobs { GatherJob j[3]; };

__global__ void gather3(GatherJobs gj) {
  const GatherJob G = gj.j[blockIdx.z];
  int g = blockIdx.x * 256 + threadIdx.x;
  int node = g >> 6, lane = g & 63;
  size_t obase = (size_t)node * DCH + lane * 8;
  if (node >= NV) {
    us8 z = {0, 0, 0, 0, 0, 0, 0, 0};
    *(us8*)(G.hb + obase) = z;
    return;
  }
  float4 a, b;
  unpack8(*(const us8*)(G.xdst + obase), a, b);
  int i = G.off[node], s1 = G.off[node + 1];
  for (; i + 1 < s1; i += 2) {
    us8 vA = *(const us8*)(G.xsrc + (size_t)G.csrc[i]     * DCH + lane * 8);
    us8 vB = *(const us8*)(G.xsrc + (size_t)G.csrc[i + 1] * DCH + lane * 8);
    float4 a0, b0, a1, b1;
    unpack8(vA, a0, b0);
    unpack8(vB, a1, b1);
    a.x += a0.x + a1.x; a.y += a0.y + a1.y; a.z += a0.z + a1.z; a.w += a0.w + a1.w;
    b.x += b0.x + b1.x; b.y += b0.y + b1.y; b.z += b0.z + b1.z; b.w += b0.w + b1.w;
  }
  if (i < s1) {
    us8 v = *(const us8*)(G.xsrc + (size_t)G.csrc[i] * DCH + lane * 8);
    float4 a0, b0;
    unpack8(v, a0, b0);
    a.x += a0.x; a.y += a0.y; a.z += a0.z; a.w += a0.w;
    b.x += b0.x; b.y += b0.y; b.z += b0.z; b.w += b0.w;
  }
  us8 o;
  o[0] = f2bf(a.x); o[1] = f2bf(a.y); o[2] = f2bf(a.z); o[3] = f2bf(a.w);
  o[4] = f2bf(b.x); o[5] = f2bf(b.y); o[6] = f2bf(b.z); o[7] = f2bf(b.w);
  *(us8*)(G.hb + obase) = o;
}

// ---------------- GEMM: 256x128 tile, 8 waves, r7 K-loop structure ----------------
// Bigger M-tile cuts staging volume 25% (A staged once per K-tile for 2x rows):
// 0.9 GB vs r7's 1.2 GB at the measured ~10 TB/s L2->LDS staging ceiling.
// Per-wave math IDENTICAL to r7 (64x64 output, acc[4][4], same swizzle algebra);
// only wave->row mapping + LDS region sizes change. LDS 48KB -> 3 blocks/CU.
// Single-buffer 2-barrier K-loop (dbuf r6, 8-phase r8, direct-L2 r11, ring r13/14
// all regressed or neutral). Grid MUST be (4, 196, z): nwg=784=8*98 XCD swizzle.
struct GemmJob  { const unsigned short* A; int lda; const unsigned short* Bt; int ldb;
                  const float* bias_a; const float* bias_b; void* out; int ldc; int col_off; };
struct GemmJobs { GemmJob j[3]; };

template<int MODE>
__global__ __launch_bounds__(512) void gemm_tile(GemmJobs jobs) {
  const GemmJob J = jobs.j[blockIdx.z];
  __shared__ __align__(16) char smem[49152];
  unsigned short* As = (unsigned short*)smem;             // [256*64] bf16, 32 KB
  unsigned short* Bs = (unsigned short*)(smem + 32768);   // [128*64] bf16, 16 KB
  const int t = threadIdx.x;
  const int wave = t >> 6, lane = t & 63;
  const int wr = wave >> 1, wc = wave & 1;   // 4M x 2N waves, each 64x64 out

  // exact XCD-chunked swizzle (nwg = 784 = 8 * 98)
  const int flat = blockIdx.x + (blockIdx.y << 2);
  const int wgid = (flat & 7) * 98 + (flat >> 3);
  const int row_base = (wgid >> 2) * 256;
  const int col_base = (wgid & 3) * 128;

  const int rl = lane & 15, kq = lane >> 4;

  f32x4 acc[4][4] = {};

  const int K = J.ldb;
  const int ktiles = K >> 6;
  const unsigned short* Ap = J.A;
  const unsigned short* Bp = J.Bt;
  const int lda = J.lda, ldb = J.ldb;
  for (int kt = 0; kt < ktiles; ++kt) {
    const int k0 = kt << 6;
    // A: 2048 granules (256 rows x 8), 4 per thread
#pragma unroll
    for (int i = 0; i < 4; ++i) {
      int q = i * 512 + t;
      int r = q >> 3, c = q & 7;
      int cg = c ^ (r & 7);   // pre-swizzled global source -> linear LDS dest
      g2lds16(Ap + (size_t)(row_base + r) * lda + k0 + cg * 8, smem + q * 16);
    }
    // B: 1024 granules (128 rows x 8), 2 per thread
#pragma unroll
    for (int i = 0; i < 2; ++i) {
      int q = i * 512 + t;
      int r = q >> 3, c = q & 7;
      int cg = c ^ (r & 7);
      g2lds16(Bp + (size_t)(col_base + r) * ldb + k0 + cg * 8, smem + 32768 + q * 16);
    }
    __syncthreads();
#pragma unroll
    for (int kk = 0; kk < 2; ++kk) {
      bf16x8 af[4], bfr[4];
#pragma unroll
      for (int m = 0; m < 4; ++m) {
        int row = wr * 64 + m * 16 + rl;            // 0..255
        int cc = (kk * 4 + kq) ^ (row & 7);
        af[m] = *(const bf16x8*)&As[(row * 8 + cc) * 8];
      }
#pragma unroll
      for (int n = 0; n < 4; ++n) {
        int col = wc * 64 + n * 16 + rl;            // 0..127
        int cc = (kk * 4 + kq) ^ (col & 7);
        bfr[n] = *(const bf16x8*)&Bs[(col * 8 + cc) * 8];
      }
#pragma unroll
      for (int m = 0; m < 4; ++m)
#pragma unroll
        for (int n = 0; n < 4; ++n)
          acc[m][n] = __builtin_amdgcn_mfma_f32_16x16x32_bf16(af[m], bfr[n], acc[m][n], 0, 0, 0);
    }
    __syncthreads();
  }

  // ---- epilogue: LDS repack -> coalesced stores ----
  float bb[4];
#pragma unroll
  for (int n = 0; n < 4; ++n) {
    int col = col_base + wc * 64 + n * 16 + rl;
    bb[n] = J.bias_a[col] + ((MODE == 1 && J.bias_b) ? J.bias_b[col] : 0.0f);
  }

  if (MODE == 0) {
    // two rounds of 128 rows; tile [128][128] bf16 = 32 KB
    unsigned short* Ch = (unsigned short*)smem;
    unsigned short* out = (unsigned short*)J.out;
#pragma unroll
    for (int p = 0; p < 2; ++p) {
      __syncthreads();
      if ((wr >> 1) == p) {
        const int colL = wc * 64 + rl;
#pragma unroll
        for (int m = 0; m < 4; ++m)
#pragma unroll
          for (int n = 0; n < 4; ++n) {
            int rloc = (wr & 1) * 64 + m * 16 + kq * 4;
#pragma unroll
            for (int j = 0; j < 4; ++j) {
              float v = fmaxf(acc[m][n][j] + bb[n], 0.0f);
              Ch[(rloc + j) * 128 + colL + n * 16] = f2bf(v);
            }
          }
      }
      __syncthreads();
#pragma unroll
      for (int i = 0; i < 4; ++i) {
        int f = i * 512 + t;            // 2048 us8 granules = [128][16]
        int rloc = f >> 4, c8 = f & 15;
        us8 v = *(const us8*)&Ch[rloc * 128 + c8 * 8];
        *(us8*)&out[(size_t)(row_base + p * 128 + rloc) * J.ldc + J.col_off + col_base + c8 * 8] = v;
      }
    }
  } else {
    // four rounds of 64 rows; tile [64][128] f32 = 32 KB
    float* Cf = (float*)smem;
    float* out = (float*)J.out;
#pragma unroll
    for (int p = 0; p < 4; ++p) {
      __syncthreads();
      if (wr == p) {
        const int colL = wc * 64 + rl;
#pragma unroll
        for (int m = 0; m < 4; ++m)
#pragma unroll
          for (int n = 0; n < 4; ++n) {
            int rloc = m * 16 + kq * 4;
#pragma unroll
            for (int j = 0; j < 4; ++j)
              Cf[(rloc + j) * 128 + colL + n * 16] = acc[m][n][j] + bb[n];
          }
      }
      __syncthreads();
#pragma unroll
      for (int i = 0; i < 4; ++i) {
        int f = i * 512 + t;            // 2048 float4 granules = [64][32]
        int rloc = f >> 5, c4 = f & 31;
        int grow = row_base + p * 64 + rloc;
        if (grow < NV) {
          f32x4 v = *(const f32x4*)&Cf[rloc * 128 + c4 * 4];
          __builtin_nontemporal_store(v, (f32x4*)&out[(size_t)grow * J.ldc + col_base + c4 * 4]);
        }
      }
    }
  }
}

extern "C" void kernel_launch(void* const* d_in, const int* in_sizes, int n_in,
                              void* d_out, int out_size, void* d_ws, size_t ws_size,
                              hipStream_t stream) {
  const float* x_a  = (const float*)d_in[0];
  const float* x_b  = (const float*)d_in[1];
  const int* ei_aa  = (const int*)d_in[2];
  const int* ei_ab  = (const int*)d_in[3];
  const int* ei_ba  = (const int*)d_in[4];
  const float* w1_aa = (const float*)d_in[5];
  const float* b1_aa = (const float*)d_in[6];
  const float* w2_aa = (const float*)d_in[7];
  const float* b2_aa = (const float*)d_in[8];
  const float* w1_ab = (const float*)d_in[9];
  const float* b1_ab = (const float*)d_in[10];
  const float* w2_ab = (const float*)d_in[11];
  const float* b2_ab = (const float*)d_in[12];
  const float* w1_ba = (const float*)d_in[13];
  const float* b1_ba = (const float*)d_in[14];
  const float* w2_ba = (const float*)d_in[15];
  const float* b2_ba = (const float*)d_in[16];

  char* ws = (char*)d_ws;
  const size_t szH  = (size_t)MPAD * DCH * 2;          // bf16 [MPAD][512]
  const size_t szH2 = (size_t)MPAD * DCH * 2 * 2;      // bf16 [MPAD][1024]
  const size_t szX  = (size_t)NV * DCH * 2;            // bf16 [NV][512]
  size_t o = 0;
  unsigned short* hb_aa = (unsigned short*)(ws + o); o += szH;
  unsigned short* hb_ba = (unsigned short*)(ws + o); o += szH;
  unsigned short* hb_ab = (unsigned short*)(ws + o); o += szH;
  unsigned short* H1c   = (unsigned short*)(ws + o); o += szH2;  // [MPAD][1024]
  unsigned short* H1ab  = (unsigned short*)(ws + o); o += szH;
  unsigned short* xa16  = (unsigned short*)(ws + o); o += szX;
  unsigned short* xb16  = (unsigned short*)(ws + o); o += szX;
  unsigned short* w1t_aa = (unsigned short*)(ws + o); o += 512 * 512 * 2;
  unsigned short* w1t_ba = (unsigned short*)(ws + o); o += 512 * 512 * 2;
  unsigned short* w1t_ab = (unsigned short*)(ws + o); o += 512 * 512 * 2;
  unsigned short* w2tc   = (unsigned short*)(ws + o); o += 512 * 1024 * 2;
  unsigned short* w2t_ab = (unsigned short*)(ws + o); o += 512 * 512 * 2;

  int* counts3 = (int*)(ws + o); o += (size_t)3 * NV * 4;   // one memset

  Csr3 cs;
  const int* eis[3] = { ei_aa, ei_ab, ei_ba };
  for (int tI = 0; tI < 3; ++tI) {
    cs.c[tI].ei     = eis[tI];
    cs.c[tI].counts = counts3 + (size_t)tI * NV;
    cs.c[tI].cursor = (int*)(ws + o); o += (size_t)NV * 4;
    cs.c[tI].incl   = (int*)(ws + o); o += (size_t)NV * 4;
    cs.c[tI].off    = (int*)(ws + o); o += ((size_t)NV + 4) * 4;
    cs.c[tI].csrc   = (int*)(ws + o); o += (size_t)NEDGE * 4;
    cs.c[tI].bsum   = (int*)(ws + o); o += 64 * 4;
  }

  float* out_a = (float*)d_out;
  float* out_b = out_a + (size_t)NV * DCH;

  WtJobs wj;
  wj.j[0] = { w1_aa, w1t_aa, 512, 0 };
  wj.j[1] = { w1_ba, w1t_ba, 512, 0 };
  wj.j[2] = { w1_ab, w1t_ab, 512, 0 };
  wj.j[3] = { w2_aa, w2tc, 1024, 0 };
  wj.j[4] = { w2_ba, w2tc, 1024, 512 };
  wj.j[5] = { w2_ab, w2t_ab, 512, 0 };

  // 1) zero histograms
  (void)hipMemsetAsync(counts3, 0, (size_t)3 * NV * 4, stream);
  // 2) prep: wt + cvt_x + hist in one launch (independent segments)
  prep_k<<<32905, 256, 0, stream>>>(wj, cs, x_a, x_b, xa16, xb16);
  // 3-5) CSR: scan1, scan3', fill
  scan1<<<dim3(49, 1, 3), 1024, 0, stream>>>(cs);
  scan3<<<dim3(196, 1, 3), 256, 0, stream>>>(cs);
  fill_csr<<<dim3(587, 1, 3), 256, 0, stream>>>(cs);
  // 6) gather, one wave per (node, type): z=0 aa (a<-a), z=1 ba (a<-b), z=2 ab (b<-a)
  GatherJobs gj;
  gj.j[0] = { xa16, xa16, cs.c[0].off, cs.c[0].csrc, hb_aa };
  gj.j[1] = { xa16, xb16, cs.c[2].off, cs.c[2].csrc, hb_ba };
  gj.j[2] = { xb16, xa16, cs.c[1].off, cs.c[1].csrc, hb_ab };
  gather3<<<dim3(MPAD / 4, 1, 3), 256, 0, stream>>>(gj);

  // 7) layer 1: 3 GEMMs in one launch (K=512)
  GemmJobs g1;
  g1.j[0] = { hb_aa, 512, w1t_aa, 512, b1_aa, nullptr, H1c,  1024, 0 };
  g1.j[1] = { hb_ba, 512, w1t_ba, 512, b1_ba, nullptr, H1c,  1024, 512 };
  g1.j[2] = { hb_ab, 512, w1t_ab, 512, b1_ab, nullptr, H1ab, 512,  0 };
  gemm_tile<0><<<dim3(4, 196, 3), 512, 0, stream>>>(g1);

  // 8) layer 2: merged-K GEMM (aa+ba, K=1024) and ab GEMM (K=512)
  GemmJobs g2;
  g2.j[0] = { H1c,  1024, w2tc,   1024, b2_aa, b2_ba,  out_a, 512, 0 };
  g2.j[1] = { H1ab, 512,  w2t_ab, 512,  b2_ab, nullptr, out_b, 512, 0 };
  g2.j[2] = g2.j[1];   // unused (grid z=2)
  gemm_tile<1><<<dim3(4, 196, 2), 512, 0, stream>>>(g2);
}

// Round 16
// 417.921 us; speedup vs baseline: 1.0788x; 1.0261x over previous
//
#include <hip/hip_runtime.h>

#define NV    50000
#define DCH   512
#define NEDGE 150000
#define MPAD  50176   // 392 * 128 = 196 * 256

typedef float  f32x4  __attribute__((ext_vector_type(4)));
typedef __bf16 bf16x8 __attribute__((ext_vector_type(8)));
typedef unsigned short us8 __attribute__((ext_vector_type(8)));

__device__ __forceinline__ unsigned short f2bf(float f) {
  unsigned int u = __builtin_bit_cast(unsigned int, f);
  u += 0x7fffu + ((u >> 16) & 1u);
  return (unsigned short)(u >> 16);
}

__device__ __forceinline__ float bf2f(unsigned short h) {
  return __builtin_bit_cast(float, (unsigned int)h << 16);
}

__device__ __forceinline__ void g2lds16(const void* g, void* l) {
  typedef const __attribute__((address_space(1))) unsigned int* gp_t;
  typedef __attribute__((address_space(3))) unsigned int* lp_t;
  __builtin_amdgcn_global_load_lds((gp_t)g, (lp_t)l, 16, 0, 0);
}

__device__ __forceinline__ void unpack8(us8 v, float4& a, float4& b) {
  a.x = bf2f(v[0]); a.y = bf2f(v[1]); a.z = bf2f(v[2]); a.w = bf2f(v[3]);
  b.x = bf2f(v[4]); b.y = bf2f(v[5]); b.z = bf2f(v[6]); b.w = bf2f(v[7]);
}

// ---------------- structs ----------------
struct WtJob  { const float* w; unsigned short* dst; int ldk, koff; };
struct WtJobs { WtJob j[6]; };
struct CsrP  { const int* ei; int* counts; int* cursor; int* incl; int* off; int* csrc; int* bsum; };
struct Csr3  { CsrP c[3]; };

// ---------------- prep mega-kernel: wt (6 jobs) + cvt_x (2) + hist (3) ----------------
__global__ void prep_k(WtJobs wj, Csr3 cs,
                       const float* __restrict__ xa, const float* __restrict__ xb,
                       unsigned short* __restrict__ oa, unsigned short* __restrict__ ob) {
  int b = blockIdx.x, tid = threadIdx.x;
  if (b < 6144) {
    const WtJob J = wj.j[b >> 10];
    int idx = (b & 1023) * 256 + tid;        // 1024*256 == 512*512 exact
    int k = idx >> 9, n = idx & 511;
    J.dst[(size_t)n * J.ldk + J.koff + k] = f2bf(J.w[(size_t)k * 512 + n]);
  } else if (b < 31144) {
    int rel = b - 6144;
    const float* s = (rel < 12500) ? xa : xb;
    unsigned short* d = (rel < 12500) ? oa : ob;
    int i = (rel % 12500) * 256 + tid;       // 12500*256 == NV*DCH/8 exact
    const float* sp = s + (size_t)i * 8;
    f32x4 u = __builtin_nontemporal_load((const f32x4*)sp);
    f32x4 v = __builtin_nontemporal_load((const f32x4*)(sp + 4));
    us8 o;
    o[0] = f2bf(u[0]); o[1] = f2bf(u[1]); o[2] = f2bf(u[2]); o[3] = f2bf(u[3]);
    o[4] = f2bf(v[0]); o[5] = f2bf(v[1]); o[6] = f2bf(v[2]); o[7] = f2bf(v[3]);
    *(us8*)(d + (size_t)i * 8) = o;
  } else {
    int rel = b - 31144;
    const CsrP C = cs.c[rel / 587];
    int e = (rel % 587) * 256 + tid;
    if (e < NEDGE) atomicAdd(&C.counts[C.ei[NEDGE + e]], 1);
  }
}

// ---------------- CSR scans (z-batched over the 3 edge types) ----------------
__global__ void scan1(Csr3 cs) {
  const CsrP C = cs.c[blockIdx.z];
  __shared__ int sm[1024];
  int t = threadIdx.x, b = blockIdx.x;
  int i = b * 1024 + t;
  int v = (i < NV) ? C.counts[i] : 0;
  sm[t] = v; __syncthreads();
  for (int off = 1; off < 1024; off <<= 1) {
    int x = sm[t];
    int y = (t >= off) ? sm[t - off] : 0;
    __syncthreads();
    sm[t] = x + y;
    __syncthreads();
  }
  if (i < NV) C.incl[i] = sm[t];
  if (t == 1023) C.bsum[b] = sm[t];
}

// scan3': folds the 49-block prefix into each thread's local sum.
__global__ void scan3(Csr3 cs) {
  const CsrP C = cs.c[blockIdx.z];
  int i = blockIdx.x * 256 + threadIdx.x;
  if (i < NV) {
    int nb = i >> 10;
    int run = 0;
    for (int j = 0; j < nb; ++j) run += C.bsum[j];
    int v = C.incl[i] - C.counts[i] + run;
    C.off[i] = v;
    C.cursor[i] = v;
  } else if (i == NV) {
    C.off[NV] = NEDGE;
  }
}

__global__ void fill_csr(Csr3 cs) {
  const CsrP C = cs.c[blockIdx.z];
  int e = blockIdx.x * 256 + threadIdx.x;
  if (e >= NEDGE) return;
  int d = C.ei[NEDGE + e];
  int pos = atomicAdd(&C.cursor[d], 1);
  C.csrc[pos] = C.ei[e];
}

// ---------------- gather, split per (node, edge-type): z in {0:aa, 1:ba, 2:ab} ----
struct GatherJob { const unsigned short* xdst; const unsigned short* xsrc;
                   const int* off; const int* csrc; unsigned short* hb; };
struct GatherJobs { GatherJob j[3]; };

__global__ void gather3(GatherJobs gj) {
  const GatherJob G = gj.j[blockIdx.z];
  int g = blockIdx.x * 256 + threadIdx.x;
  int node = g >> 6, lane = g & 63;
  size_t obase = (size_t)node * DCH + lane * 8;
  if (node >= NV) {
    us8 z = {0, 0, 0, 0, 0, 0, 0, 0};
    *(us8*)(G.hb + obase) = z;
    return;
  }
  float4 a, b;
  unpack8(*(const us8*)(G.xdst + obase), a, b);
  int i = G.off[node], s1 = G.off[node + 1];
  for (; i + 1 < s1; i += 2) {
    us8 vA = *(const us8*)(G.xsrc + (size_t)G.csrc[i]     * DCH + lane * 8);
    us8 vB = *(const us8*)(G.xsrc + (size_t)G.csrc[i + 1] * DCH + lane * 8);
    float4 a0, b0, a1, b1;
    unpack8(vA, a0, b0);
    unpack8(vB, a1, b1);
    a.x += a0.x + a1.x; a.y += a0.y + a1.y; a.z += a0.z + a1.z; a.w += a0.w + a1.w;
    b.x += b0.x + b1.x; b.y += b0.y + b1.y; b.z += b0.z + b1.z; b.w += b0.w + b1.w;
  }
  if (i < s1) {
    us8 v = *(const us8*)(G.xsrc + (size_t)G.csrc[i] * DCH + lane * 8);
    float4 a0, b0;
    unpack8(v, a0, b0);
    a.x += a0.x; a.y += a0.y; a.z += a0.z; a.w += a0.w;
    b.x += b0.x; b.y += b0.y; b.z += b0.z; b.w += b0.w;
  }
  us8 o;
  o[0] = f2bf(a.x); o[1] = f2bf(a.y); o[2] = f2bf(a.z); o[3] = f2bf(a.w);
  o[4] = f2bf(b.x); o[5] = f2bf(b.y); o[6] = f2bf(b.z); o[7] = f2bf(b.w);
  *(us8*)(G.hb + obase) = o;
}

// ---------------- GEMM (r10/r12 structure, measured best: 122 us/launch) ----------
// 128x128 tile, BK=64, 4 waves (2x2), 16x16x32 bf16 MFMA; single-buffer K-loop.
// Falsified alternatives: dbuf/1-barrier (r6 -12%), 8-phase 256^2 (r8 0%),
// direct-L2 fragments (r11 -160%: LDS staging IS the request coalescer),
// BK=32 4-buf ring w/ counted vmcnt (r14 -20%: fence+LDS overhead), 256x128
// (r15 -5%). This is the local optimum for K<=1024 at these shapes.
// LDS-repack coalesced epilogue. Grid MUST be (4, 392, z): nwg=1568=8*196 swizzle.
struct GemmJob  { const unsigned short* A; int lda; const unsigned short* Bt; int ldb;
                  const float* bias_a; const float* bias_b; void* out; int ldc; int col_off; };
struct GemmJobs { GemmJob j[3]; };

template<int MODE>
__global__ void gemm_tile(GemmJobs jobs) {
  const GemmJob J = jobs.j[blockIdx.z];
  __shared__ __align__(16) char smem[32768];
  unsigned short* As = (unsigned short*)smem;             // [128*64] bf16, 16 KB
  unsigned short* Bs = (unsigned short*)(smem + 16384);   // [128*64] bf16, 16 KB
  const int t = threadIdx.x;
  const int wave = t >> 6, lane = t & 63;
  const int wr = wave >> 1, wc = wave & 1;

  // exact XCD-chunked swizzle (nwg = 1568 = 8 * 196)
  const int flat = blockIdx.x + (blockIdx.y << 2);
  const int wgid = (flat & 7) * 196 + (flat >> 3);
  const int row_base = (wgid >> 2) * 128;
  const int col_base = (wgid & 3) * 128;

  const int rl = lane & 15, kq = lane >> 4;

  f32x4 acc[4][4] = {};

  const int K = J.ldb;
  const int ktiles = K >> 6;
  const unsigned short* Ap = J.A;
  const unsigned short* Bp = J.Bt;
  const int lda = J.lda, ldb = J.ldb;
  for (int kt = 0; kt < ktiles; ++kt) {
    const int k0 = kt << 6;
#pragma unroll
    for (int i = 0; i < 4; ++i) {
      int q = i * 256 + t;
      int r = q >> 3, c = q & 7;
      int cg = c ^ (r & 7);   // pre-swizzled global source -> linear LDS dest
      g2lds16(Ap + (size_t)(row_base + r) * lda + k0 + cg * 8,
              &As[(size_t)(i * 256 + wave * 64) * 8]);
      g2lds16(Bp + (size_t)(col_base + r) * ldb + k0 + cg * 8,
              &Bs[(size_t)(i * 256 + wave * 64) * 8]);
    }
    __syncthreads();
#pragma unroll
    for (int kk = 0; kk < 2; ++kk) {
      bf16x8 af[4], bfr[4];
#pragma unroll
      for (int m = 0; m < 4; ++m) {
        int row = wr * 64 + m * 16 + rl;
        int cc = (kk * 4 + kq) ^ (row & 7);
        af[m] = *(const bf16x8*)&As[(row * 8 + cc) * 8];
      }
#pragma unroll
      for (int n = 0; n < 4; ++n) {
        int col = wc * 64 + n * 16 + rl;
        int cc = (kk * 4 + kq) ^ (col & 7);
        bfr[n] = *(const bf16x8*)&Bs[(col * 8 + cc) * 8];
      }
#pragma unroll
      for (int m = 0; m < 4; ++m)
#pragma unroll
        for (int n = 0; n < 4; ++n)
          acc[m][n] = __builtin_amdgcn_mfma_f32_16x16x32_bf16(af[m], bfr[n], acc[m][n], 0, 0, 0);
    }
    __syncthreads();
  }

  // ---- epilogue: LDS repack -> coalesced stores ----
  float bb[4];
#pragma unroll
  for (int n = 0; n < 4; ++n) {
    int col = col_base + wc * 64 + n * 16 + rl;
    bb[n] = J.bias_a[col] + ((MODE == 1 && J.bias_b) ? J.bias_b[col] : 0.0f);
  }

  if (MODE == 0) {
    unsigned short* Ch = (unsigned short*)smem;   // [128][128] bf16 = 32 KB
#pragma unroll
    for (int m = 0; m < 4; ++m)
#pragma unroll
      for (int n = 0; n < 4; ++n) {
        int col = wc * 64 + n * 16 + rl;
#pragma unroll
        for (int j = 0; j < 4; ++j) {
          int row = wr * 64 + m * 16 + kq * 4 + j;
          float v = fmaxf(acc[m][n][j] + bb[n], 0.0f);
          Ch[row * 128 + col] = f2bf(v);
        }
      }
    __syncthreads();
    unsigned short* out = (unsigned short*)J.out;
#pragma unroll
    for (int i = 0; i < 8; ++i) {
      int f = i * 256 + t;            // us8 granules, 2048 total
      int rloc = f >> 4, c8 = f & 15;
      us8 v = *(const us8*)&Ch[rloc * 128 + c8 * 8];
      *(us8*)&out[(size_t)(row_base + rloc) * J.ldc + J.col_off + col_base + c8 * 8] = v;
    }
  } else {
    float* Cf = (float*)smem;                     // [64][128] f32 per round
    float* out = (float*)J.out;
#pragma unroll
    for (int p = 0; p < 2; ++p) {
      __syncthreads();
      if (wr == p) {
#pragma unroll
        for (int m = 0; m < 4; ++m)
#pragma unroll
          for (int n = 0; n < 4; ++n) {
            int col = wc * 64 + n * 16 + rl;
#pragma unroll
            for (int j = 0; j < 4; ++j) {
              int rloc = m * 16 + kq * 4 + j;
              Cf[rloc * 128 + col] = acc[m][n][j] + bb[n];
            }
          }
      }
      __syncthreads();
#pragma unroll
      for (int i = 0; i < 8; ++i) {
        int f = i * 256 + t;          // float4 granules, 2048 total
        int rloc = f >> 5, c4 = f & 31;
        int grow = row_base + p * 64 + rloc;
        if (grow < NV) {
          f32x4 v = *(const f32x4*)&Cf[rloc * 128 + c4 * 4];
          __builtin_nontemporal_store(v, (f32x4*)&out[(size_t)grow * J.ldc + col_base + c4 * 4]);
        }
      }
    }
  }
}

extern "C" void kernel_launch(void* const* d_in, const int* in_sizes, int n_in,
                              void* d_out, int out_size, void* d_ws, size_t ws_size,
                              hipStream_t stream) {
  const float* x_a  = (const float*)d_in[0];
  const float* x_b  = (const float*)d_in[1];
  const int* ei_aa  = (const int*)d_in[2];
  const int* ei_ab  = (const int*)d_in[3];
  const int* ei_ba  = (const int*)d_in[4];
  const float* w1_aa = (const float*)d_in[5];
  const float* b1_aa = (const float*)d_in[6];
  const float* w2_aa = (const float*)d_in[7];
  const float* b2_aa = (const float*)d_in[8];
  const float* w1_ab = (const float*)d_in[9];
  const float* b1_ab = (const float*)d_in[10];
  const float* w2_ab = (const float*)d_in[11];
  const float* b2_ab = (const float*)d_in[12];
  const float* w1_ba = (const float*)d_in[13];
  const float* b1_ba = (const float*)d_in[14];
  const float* w2_ba = (const float*)d_in[15];
  const float* b2_ba = (const float*)d_in[16];

  char* ws = (char*)d_ws;
  const size_t szH  = (size_t)MPAD * DCH * 2;          // bf16 [MPAD][512]
  const size_t szH2 = (size_t)MPAD * DCH * 2 * 2;      // bf16 [MPAD][1024]
  const size_t szX  = (size_t)NV * DCH * 2;            // bf16 [NV][512]
  size_t o = 0;
  unsigned short* hb_aa = (unsigned short*)(ws + o); o += szH;
  unsigned short* hb_ba = (unsigned short*)(ws + o); o += szH;
  unsigned short* hb_ab = (unsigned short*)(ws + o); o += szH;
  unsigned short* H1c   = (unsigned short*)(ws + o); o += szH2;  // [MPAD][1024]
  unsigned short* H1ab  = (unsigned short*)(ws + o); o += szH;
  unsigned short* xa16  = (unsigned short*)(ws + o); o += szX;
  unsigned short* xb16  = (unsigned short*)(ws + o); o += szX;
  unsigned short* w1t_aa = (unsigned short*)(ws + o); o += 512 * 512 * 2;
  unsigned short* w1t_ba = (unsigned short*)(ws + o); o += 512 * 512 * 2;
  unsigned short* w1t_ab = (unsigned short*)(ws + o); o += 512 * 512 * 2;
  unsigned short* w2tc   = (unsigned short*)(ws + o); o += 512 * 1024 * 2;
  unsigned short* w2t_ab = (unsigned short*)(ws + o); o += 512 * 512 * 2;

  int* counts3 = (int*)(ws + o); o += (size_t)3 * NV * 4;   // one memset

  Csr3 cs;
  const int* eis[3] = { ei_aa, ei_ab, ei_ba };
  for (int tI = 0; tI < 3; ++tI) {
    cs.c[tI].ei     = eis[tI];
    cs.c[tI].counts = counts3 + (size_t)tI * NV;
    cs.c[tI].cursor = (int*)(ws + o); o += (size_t)NV * 4;
    cs.c[tI].incl   = (int*)(ws + o); o += (size_t)NV * 4;
    cs.c[tI].off    = (int*)(ws + o); o += ((size_t)NV + 4) * 4;
    cs.c[tI].csrc   = (int*)(ws + o); o += (size_t)NEDGE * 4;
    cs.c[tI].bsum   = (int*)(ws + o); o += 64 * 4;
  }

  float* out_a = (float*)d_out;
  float* out_b = out_a + (size_t)NV * DCH;

  WtJobs wj;
  wj.j[0] = { w1_aa, w1t_aa, 512, 0 };
  wj.j[1] = { w1_ba, w1t_ba, 512, 0 };
  wj.j[2] = { w1_ab, w1t_ab, 512, 0 };
  wj.j[3] = { w2_aa, w2tc, 1024, 0 };
  wj.j[4] = { w2_ba, w2tc, 1024, 512 };
  wj.j[5] = { w2_ab, w2t_ab, 512, 0 };

  // 1) zero histograms
  (void)hipMemsetAsync(counts3, 0, (size_t)3 * NV * 4, stream);
  // 2) prep: wt + cvt_x + hist in one launch (independent segments)
  prep_k<<<32905, 256, 0, stream>>>(wj, cs, x_a, x_b, xa16, xb16);
  // 3-5) CSR: scan1, scan3', fill
  scan1<<<dim3(49, 1, 3), 1024, 0, stream>>>(cs);
  scan3<<<dim3(196, 1, 3), 256, 0, stream>>>(cs);
  fill_csr<<<dim3(587, 1, 3), 256, 0, stream>>>(cs);
  // 6) gather, one wave per (node, type): z=0 aa (a<-a), z=1 ba (a<-b), z=2 ab (b<-a)
  GatherJobs gj;
  gj.j[0] = { xa16, xa16, cs.c[0].off, cs.c[0].csrc, hb_aa };
  gj.j[1] = { xa16, xb16, cs.c[2].off, cs.c[2].csrc, hb_ba };
  gj.j[2] = { xb16, xa16, cs.c[1].off, cs.c[1].csrc, hb_ab };
  gather3<<<dim3(MPAD / 4, 1, 3), 256, 0, stream>>>(gj);

  // 7) layer 1: 3 GEMMs in one launch (K=512)
  GemmJobs g1;
  g1.j[0] = { hb_aa, 512, w1t_aa, 512, b1_aa, nullptr, H1c,  1024, 0 };
  g1.j[1] = { hb_ba, 512, w1t_ba, 512, b1_ba, nullptr, H1c,  1024, 512 };
  g1.j[2] = { hb_ab, 512, w1t_ab, 512, b1_ab, nullptr, H1ab, 512,  0 };
  gemm_tile<0><<<dim3(4, 392, 3), 256, 0, stream>>>(g1);

  // 8) layer 2: merged-K GEMM (aa+ba, K=1024) and ab GEMM (K=512)
  GemmJobs g2;
  g2.j[0] = { H1c,  1024, w2tc,   1024, b2_aa, b2_ba,  out_a, 512, 0 };
  g2.j[1] = { H1ab, 512,  w2t_ab, 512,  b2_ab, nullptr, out_b, 512, 0 };
  g2.j[2] = g2.j[1];   // unused (grid z=2)
  gemm_tile<1><<<dim3(4, 392, 2), 256, 0, stream>>>(g2);
}